// Round 10
// baseline (402.643 us; speedup 1.0000x reference)
//
#include <hip/hip_runtime.h>

// 1D Euler, Roe flux + Harten entropy fix, 32 steps. Round 10:
// ASYNC DATAFLOW sync (no global barrier), register-persistent state.
//
// Round-9 experiment: register-resident state cut HBM traffic 431->26 MB
// but wall time stayed 400 us => ~10 us/step is sync protocol: 4096 waves
// loading 64 IC slot dwords each step, 256 pollers on ONE flag dword, and
// a serialized two-phase rendezvous. This round replaces the barrier with
// point-to-point dataflow:
//  - Per-step halo/slot/done rows (33 each, never reused -> no WAR; blocks
//    skew freely, bounded to 1 step by the dt coupling).
//  - Neighbor handshake: hflag[b]=k+2 published after step k; only the two
//    EDGE threads of b+-1 poll it.
//  - dt: leader slotMax(row)+done[row]++ (ordered by data dependency on
//    the returned value); 256th incrementer stores ready=row+1 to 8 padded
//    copies (<=32 pollers each). Wave 0 ONLY polls ready and reads the 64
//    slots (one coalesced line burst), broadcasts amax via LDS.
//  - Flux compute overlaps the ready poll; IC ops/step drop ~12x.
// Fallbacks (occupancy-gated): round-8/9 proven barrier kernel, then
// 33 plain dispatches.

#define NXC   1048576
#define GAM   1.4f
#define GM1   0.4f
#define IGM1  2.5f
#define CFLC  0.5f
#define DXC   1e-3f
#define EFIX  0.1f
#define NSTEPS 32
#define NSLOT  (NSTEPS + 1)
#define SLOTW  64
#define BSTRIDE 32             // 128 B padding between control dwords

// Variant A (async) geometry — matches r9's launched euler_regs shape
#define ABLK  1024
#define ACPT  4
#define ATILE (ABLK*ACPT)      // 4096
#define ANBLK (NXC/ATILE)      // 256 blocks = 1/CU

// Variant B/C geometry (round 8, proven)
#define BLK   256
#define CPT   4
#define TILE  (BLK*CPT)        // 1024
#define NBLK  (NXC/TILE)       // 1024

__device__ __forceinline__ float frcp(float x){ return __builtin_amdgcn_rcpf(x); }
__device__ __forceinline__ float frsq(float x){ return __builtin_amdgcn_rsqf(x); }
__device__ __forceinline__ float fsqrt_(float x){ return __builtin_amdgcn_sqrtf(x); }

__device__ __forceinline__ float sysloadf(const float* p) {
    return __hip_atomic_load(p, __ATOMIC_RELAXED, __HIP_MEMORY_SCOPE_SYSTEM);
}
__device__ __forceinline__ void sysstoref(float* p, float v) {
    __hip_atomic_store(p, v, __ATOMIC_RELAXED, __HIP_MEMORY_SCOPE_SYSTEM);
}
__device__ __forceinline__ unsigned sysloadu(const unsigned* p) {
    return __hip_atomic_load(p, __ATOMIC_RELAXED, __HIP_MEMORY_SCOPE_SYSTEM);
}
__device__ __forceinline__ void sysstoreu(unsigned* p, unsigned v) {
    __hip_atomic_store(p, v, __ATOMIC_RELAXED, __HIP_MEMORY_SCOPE_SYSTEM);
}
__device__ __forceinline__ unsigned sysmaxu(unsigned* p, unsigned v) {
    return __hip_atomic_fetch_max(p, v, __ATOMIC_RELAXED,
                                  __HIP_MEMORY_SCOPE_SYSTEM);
}
__device__ __forceinline__ unsigned sysaddu(unsigned* p, unsigned v) {
    return __hip_atomic_fetch_add(p, v, __ATOMIC_RELAXED,
                                  __HIP_MEMORY_SCOPE_SYSTEM);
}
__device__ __forceinline__ void pollge(const unsigned* p, unsigned tgt) {
    while (sysloadu(p) < tgt) __builtin_amdgcn_s_sleep(1);
}

__device__ __forceinline__ float wave_max(float v) {
    #pragma unroll
    for (int k = 32; k >= 1; k >>= 1)
        v = fmaxf(v, __shfl_xor(v, k));
    return v;
}

// Relaxed system-scope two-level barrier (proven r4/7/8) for fallback B.
template<int L1N, int PERL1, int L2N>
__device__ __forceinline__ void gbar(unsigned* bar, int bid, unsigned gen) {
    unsigned* bar1 = bar;
    unsigned* bar2 = bar + 64 * BSTRIDE;
    unsigned* flag = bar + 65 * BSTRIDE;
    __syncthreads();
    if (threadIdx.x == 0) {
        unsigned o = sysaddu(&bar1[(bid & (L1N - 1)) * BSTRIDE], 1u);
        if ((o & (unsigned)(PERL1 - 1)) == (unsigned)(PERL1 - 1)) {
            unsigned o2 = sysaddu(bar2, 1u);
            if ((o2 & (unsigned)(L2N - 1)) == (unsigned)(L2N - 1))
                sysstoreu(flag, gen);
        }
        while (sysloadu(flag) < gen) __builtin_amdgcn_s_sleep(2);
    }
    __syncthreads();
}

// ctrl layout (uints): bar 66*32 | slots 33*64 | done 33*32 | ready 8*32 |
//                      hflag ANBLK*32 | tbuf 33
#define CTRL_BAR   0
#define CTRL_SLOTS (66*BSTRIDE)
#define CTRL_DONE  (CTRL_SLOTS + NSLOT*SLOTW)
#define CTRL_READY (CTRL_DONE + NSLOT*BSTRIDE)
#define CTRL_HFLAG (CTRL_READY + 8*BSTRIDE)
#define CTRL_TBUF  (CTRL_HFLAG + ANBLK*BSTRIDE)
#define CTRL_TOTAL (CTRL_TBUF + NSLOT)

__global__ void ws_zero(unsigned* z) {
    for (int i = threadIdx.x; i < CTRL_TOTAL; i += 256) z[i] = 0u;
}

// ---------------- shared Roe flux over a 6-cell window ----------------
__device__ __forceinline__ void roe5(const float rr[6], const float uu[6],
                                     const float pp[6], const float ss[6],
                                     const float gg[6],
                                     float Fr[5], float Fm[5], float Fe[5]) {
    #pragma unroll
    for (int j = 0; j < 5; ++j) {
        float sL = ss[j], sR = ss[j + 1];
        float uL = uu[j], uR = uu[j + 1];
        float invden = frcp(sL + sR);
        float ur = (sL * uL + sR * uR) * invden;
        float Hr = (gg[j] + gg[j + 1]) * invden;
        float c  = fsqrt_(fmaxf(GM1 * (Hr - 0.5f * ur * ur), 1e-10f));
        float eps = EFIX * c;
        float l1 = ur - c, l3 = ur + c;
        float a1 = fsqrt_(l1 * l1 + eps * eps);
        float a2 = fsqrt_(ur * ur + eps * eps);
        float a3 = fsqrt_(l3 * l3 + eps * eps);
        float drho = rr[j + 1] - rr[j];
        float du   = uR - uL;
        float dp   = pp[j + 1] - pp[j];
        float c2 = c * c;
        float inv2c2 = frcp(c2 + c2);
        float al2 = drho - (dp + dp) * inv2c2;
        float tcd = c * rr[j + 1] * du;
        float al1 = (dp - tcd) * inv2c2;
        float al3 = (dp + tcd) * inv2c2;
        float FrL = rr[j] * uL, FrR = rr[j + 1] * uR;
        float FmL = FrL * uL + pp[j], FmR = FrR * uR + pp[j + 1];
        float FeL = uL * (gg[j] * sL), FeR = uR * (gg[j + 1] * sR);
        float w1 = a1 * al1, w2 = a2 * al2, w3 = a3 * al3;
        Fr[j] = 0.5f * (FrL + FrR - (w1 + w2 + w3));
        Fm[j] = 0.5f * (FmL + FmR - (w1 * l1 + w2 * ur + w3 * l3));
        Fe[j] = 0.5f * (FeL + FeR - (w1 * (Hr - ur * c) + w2 * (0.5f * ur * ur)
                                     + w3 * (Hr + ur * c)));
    }
}

// ================= Variant A: async dataflow, register state =============
__global__ __launch_bounds__(ABLK, 4) void euler_async(
        const float* __restrict__ rho0, const float* __restrict__ u0,
        const float* __restrict__ p0, const float* __restrict__ tf,
        float* __restrict__ out, unsigned* __restrict__ ctrl,
        float* __restrict__ halo) {   // halo: NSLOT rows x ANBLK x 6
    __shared__ float Lr[ABLK], Lu[ABLK], Lp[ABLK];   // each thread's cell3
    __shared__ float Rr[ABLK], Ru[ABLK], Rp[ABLK];   // each thread's cell0
    __shared__ float red[ABLK / 64];
    __shared__ float samax;
    unsigned* slots = ctrl + CTRL_SLOTS;
    unsigned* done  = ctrl + CTRL_DONE;
    unsigned* ready = ctrl + CTRL_READY;
    unsigned* hflag = ctrl + CTRL_HFLAG;

    const int tid = threadIdx.x, bid = blockIdx.x;
    const int c0 = bid * ATILE + ACPT * tid;
    const int lane = tid & 63, wid = tid >> 6;

    float cr[4], cu[4], cp[4];

    // ---- prepass: inputs -> regs; publish halo row 0, slot row 0 ----
    {
        float4 r4 = *(const float4*)(rho0 + c0);
        float4 u4 = *(const float4*)(u0 + c0);
        float4 p4 = *(const float4*)(p0 + c0);
        cr[0]=r4.x; cr[1]=r4.y; cr[2]=r4.z; cr[3]=r4.w;
        cu[0]=u4.x; cu[1]=u4.y; cu[2]=u4.z; cu[3]=u4.w;
        cp[0]=p4.x; cp[1]=p4.y; cp[2]=p4.z; cp[3]=p4.w;
        float nm = 0.f;
        #pragma unroll
        for (int c = 0; c < 4; ++c)
            nm = fmaxf(nm, fabsf(cu[c]) + fsqrt_(GAM * cp[c] * frcp(cr[c])));
        Lr[tid]=cr[3]; Lu[tid]=cu[3]; Lp[tid]=cp[3];
        Rr[tid]=cr[0]; Ru[tid]=cu[0]; Rp[tid]=cp[0];
        if (tid == 0) {
            float* h = halo + (size_t)bid * 6;
            sysstoref(h, cr[0]); sysstoref(h+1, cu[0]); sysstoref(h+2, cp[0]);
        }
        if (tid == ABLK - 1) {
            float* h = halo + (size_t)bid * 6 + 3;
            sysstoref(h, cr[3]); sysstoref(h+1, cu[3]); sysstoref(h+2, cp[3]);
        }
        nm = wave_max(nm);
        if (lane == 0) red[wid] = nm;
        __syncthreads();            // drains halo stores (vmcnt) + red[]
        if (tid == 0) {
            float bm = red[0];
            #pragma unroll
            for (int w = 1; w < ABLK / 64; ++w) bm = fmaxf(bm, red[w]);
            sysstoreu(&hflag[bid * BSTRIDE], 1u);     // halo row 0 published
            unsigned om = sysmaxu(&slots[bid & (SLOTW - 1)],
                                  __float_as_uint(bm));
            unsigned od = sysaddu(&done[0], 1u + (om >> 31));  // dep-ordered
            if (od == ANBLK - 1) {
                unsigned v = 1u + (od >> 31);          // "rows <= 0 final"
                #pragma unroll
                for (int j = 0; j < 8; ++j) sysstoreu(&ready[j * BSTRIDE], v);
            }
        }
    }
    float t = 0.f;
    const float tfin = *tf;

    for (int k = 0; k < NSTEPS; ++k) {
        // window: idx 0..5 = cells c0-1 .. c0+4 (state k)
        float rr[6], uu[6], pp[6];
        #pragma unroll
        for (int c = 0; c < 4; ++c) { rr[c+1]=cr[c]; uu[c+1]=cu[c]; pp[c+1]=cp[c]; }
        if (tid == 0) {
            if (bid > 0) {
                pollge(&hflag[(bid - 1) * BSTRIDE], (unsigned)(k + 1));
                const float* h = halo + ((size_t)k * ANBLK + (bid - 1)) * 6 + 3;
                rr[0]=sysloadf(h); uu[0]=sysloadf(h+1); pp[0]=sysloadf(h+2);
            } else { rr[0]=cr[0]; uu[0]=cu[0]; pp[0]=cp[0]; }
        } else { rr[0]=Lr[tid-1]; uu[0]=Lu[tid-1]; pp[0]=Lp[tid-1]; }
        if (tid == ABLK - 1) {
            if (bid < ANBLK - 1) {
                pollge(&hflag[(bid + 1) * BSTRIDE], (unsigned)(k + 1));
                const float* h = halo + ((size_t)k * ANBLK + (bid + 1)) * 6;
                rr[5]=sysloadf(h); uu[5]=sysloadf(h+1); pp[5]=sysloadf(h+2);
            } else { rr[5]=cr[3]; uu[5]=cu[3]; pp[5]=cp[3]; }
        } else { rr[5]=Rr[tid+1]; uu[5]=Ru[tid+1]; pp[5]=Rp[tid+1]; }

        // flux compute (overlaps wave0's later ready-poll on other waves)
        float ss[6], gg[6];
        #pragma unroll
        for (int i = 0; i < 6; ++i) {
            float E = pp[i] * IGM1 + 0.5f * rr[i] * uu[i] * uu[i];
            float q = frsq(rr[i]);
            ss[i] = rr[i] * q;
            gg[i] = (E + pp[i]) * q;
        }
        float Fr[5], Fm[5], Fe[5];
        roe5(rr, uu, pp, ss, gg, Fr, Fm, Fe);

        // wave 0: wait for slot row k finality, read 64 slots, broadcast
        if (wid == 0) {
            pollge(&ready[(bid & 7) * BSTRIDE], (unsigned)(k + 1));
            float av = __uint_as_float(sysloadu(&slots[(size_t)k * SLOTW + lane]));
            float am = wave_max(av);
            if (lane == 0) samax = am;
        }
        __syncthreads();     // #1: sdt ready; all LDS neighbor reads done

        float amax = samax;
        float dt = fminf(CFLC * DXC / amax, fmaxf(tfin - t, 0.f));
        t += dt;
        float dtdx = dt / DXC;

        float nm = 0.f;
        #pragma unroll
        for (int i = 1; i <= 4; ++i) {
            float E  = gg[i] * ss[i] - pp[i];           // (E+p) - p
            float r2 = rr[i]         - dtdx * (Fr[i] - Fr[i-1]);
            float m2 = rr[i] * uu[i] - dtdx * (Fm[i] - Fm[i-1]);
            float E2 = E             - dtdx * (Fe[i] - Fe[i-1]);
            float q2 = frsq(r2);
            float ir = q2 * q2;
            float u2 = m2 * ir;
            float p2 = GM1 * (E2 - 0.5f * r2 * u2 * u2);
            cr[i-1]=r2; cu[i-1]=u2; cp[i-1]=p2;
            nm = fmaxf(nm, fabsf(u2) + fsqrt_(GAM * p2 * ir));
        }

        if (k < NSTEPS - 1) {
            Lr[tid]=cr[3]; Lu[tid]=cu[3]; Lp[tid]=cp[3];
            Rr[tid]=cr[0]; Ru[tid]=cu[0]; Rp[tid]=cp[0];
            if (tid == 0) {
                float* h = halo + ((size_t)(k + 1) * ANBLK + bid) * 6;
                sysstoref(h, cr[0]); sysstoref(h+1, cu[0]); sysstoref(h+2, cp[0]);
            }
            if (tid == ABLK - 1) {
                float* h = halo + ((size_t)(k + 1) * ANBLK + bid) * 6 + 3;
                sysstoref(h, cr[3]); sysstoref(h+1, cu[3]); sysstoref(h+2, cp[3]);
            }
            nm = wave_max(nm);
            if (lane == 0) red[wid] = nm;
            __syncthreads();   // #2: drains halo stores; LDS visible next step
            if (tid == 0) {
                float bm = red[0];
                #pragma unroll
                for (int w = 1; w < ABLK / 64; ++w) bm = fmaxf(bm, red[w]);
                sysstoreu(&hflag[bid * BSTRIDE], (unsigned)(k + 2));
                unsigned om = sysmaxu(&slots[(size_t)(k + 1) * SLOTW
                                             + (bid & (SLOTW - 1))],
                                      __float_as_uint(bm));
                unsigned od = sysaddu(&done[(size_t)(k + 1) * BSTRIDE],
                                      1u + (om >> 31));
                if (od == ANBLK - 1) {
                    unsigned v = (unsigned)(k + 2) + (od >> 31);
                    #pragma unroll
                    for (int j = 0; j < 8; ++j)
                        sysstoreu(&ready[j * BSTRIDE], v);
                }
            }
        } else {
            *(float4*)(out + c0)         = make_float4(cr[0], cr[1], cr[2], cr[3]);
            *(float4*)(out + NXC + c0)   = make_float4(cu[0], cu[1], cu[2], cu[3]);
            *(float4*)(out + 2*NXC + c0) = make_float4(cp[0], cp[1], cp[2], cp[3]);
        }
    }
}

// ================= Variant B/C: round-8/9 reload design (proven) =========
__device__ __forceinline__ void prepass_core(
        const float* __restrict__ rho0, const float* __restrict__ u0,
        const float* __restrict__ p0, unsigned* __restrict__ slots,
        float* __restrict__ red) {
    const int tid = threadIdx.x, bid = blockIdx.x;
    const int c0 = bid * TILE + CPT * tid;
    float4 r4 = *(const float4*)(rho0 + c0);
    float4 u4 = *(const float4*)(u0 + c0);
    float4 p4 = *(const float4*)(p0 + c0);
    const float ra[4] = {r4.x, r4.y, r4.z, r4.w};
    const float ua[4] = {u4.x, u4.y, u4.z, u4.w};
    const float pa[4] = {p4.x, p4.y, p4.z, p4.w};
    float nm = 0.f;
    #pragma unroll
    for (int c = 0; c < CPT; ++c)
        nm = fmaxf(nm, fabsf(ua[c]) + fsqrt_(GAM * pa[c] * frcp(ra[c])));
    nm = wave_max(nm);
    if ((tid & 63) == 0) red[tid >> 6] = nm;
    __syncthreads();
    if (tid == 0)
        sysmaxu(&slots[(size_t)(bid & (SLOTW - 1))],
                __float_as_uint(fmaxf(fmaxf(red[0], red[1]),
                                      fmaxf(red[2], red[3]))));
}

__device__ __forceinline__ float step_core(
        int k, int bid, int tid,
        const float* __restrict__ rs, const float* __restrict__ us,
        const float* __restrict__ ps, float* __restrict__ dst,
        const float* __restrict__ hin, float* __restrict__ hout,
        unsigned* __restrict__ slots, float t, float tfin,
        float* __restrict__ red) {
    const int c0 = bid * TILE + CPT * tid;
    float av = __uint_as_float(
        sysloadu(&slots[(size_t)k * SLOTW + (tid & (SLOTW - 1))]));
    float rr[6], uu[6], pp[6];
    {
        float4 r4 = *(const float4*)(rs + c0);
        float4 u4 = *(const float4*)(us + c0);
        float4 p4 = *(const float4*)(ps + c0);
        rr[1]=r4.x; rr[2]=r4.y; rr[3]=r4.z; rr[4]=r4.w;
        uu[1]=u4.x; uu[2]=u4.y; uu[3]=u4.z; uu[4]=u4.w;
        pp[1]=p4.x; pp[2]=p4.y; pp[3]=p4.z; pp[4]=p4.w;
    }
    if (k > 0 && tid == 0 && bid > 0) {
        const float* h = hin + (size_t)(bid - 1) * 6 + 3;
        rr[0]=sysloadf(h); uu[0]=sysloadf(h+1); pp[0]=sysloadf(h+2);
    } else {
        int g = max(c0 - 1, 0);
        rr[0]=rs[g]; uu[0]=us[g]; pp[0]=ps[g];
    }
    if (k > 0 && tid == BLK - 1 && bid < NBLK - 1) {
        const float* h = hin + (size_t)(bid + 1) * 6;
        rr[5]=sysloadf(h); uu[5]=sysloadf(h+1); pp[5]=sysloadf(h+2);
    } else {
        int g = min(c0 + CPT, NXC - 1);
        rr[5]=rs[g]; uu[5]=us[g]; pp[5]=ps[g];
    }
    float ss[6], gg[6];
    #pragma unroll
    for (int i = 0; i < 6; ++i) {
        float E = pp[i] * IGM1 + 0.5f * rr[i] * uu[i] * uu[i];
        float q = frsq(rr[i]);
        ss[i] = rr[i] * q;
        gg[i] = (E + pp[i]) * q;
    }
    float Fr[5], Fm[5], Fe[5];
    roe5(rr, uu, pp, ss, gg, Fr, Fm, Fe);
    float amax = wave_max(av);
    float dt = fminf(CFLC * DXC / amax, fmaxf(tfin - t, 0.f));
    float dtdx = dt / DXC;
    float o_r[4], o_u[4], o_p[4];
    float nm = 0.f;
    #pragma unroll
    for (int i = 1; i <= 4; ++i) {
        float E  = gg[i] * ss[i] - pp[i];
        float r2 = rr[i]         - dtdx * (Fr[i] - Fr[i-1]);
        float m2 = rr[i] * uu[i] - dtdx * (Fm[i] - Fm[i-1]);
        float E2 = E             - dtdx * (Fe[i] - Fe[i-1]);
        float q2 = frsq(r2);
        float ir = q2 * q2;
        float u2 = m2 * ir;
        float p2 = GM1 * (E2 - 0.5f * r2 * u2 * u2);
        o_r[i-1]=r2; o_u[i-1]=u2; o_p[i-1]=p2;
        nm = fmaxf(nm, fabsf(u2) + fsqrt_(GAM * p2 * ir));
    }
    *(float4*)(dst + c0)         = make_float4(o_r[0], o_r[1], o_r[2], o_r[3]);
    *(float4*)(dst + NXC + c0)   = make_float4(o_u[0], o_u[1], o_u[2], o_u[3]);
    *(float4*)(dst + 2*NXC + c0) = make_float4(o_p[0], o_p[1], o_p[2], o_p[3]);
    if (tid == 0) {
        float* h = hout + (size_t)bid * 6;
        sysstoref(h, o_r[0]); sysstoref(h+1, o_u[0]); sysstoref(h+2, o_p[0]);
    }
    if (tid == BLK - 1) {
        float* h = hout + (size_t)bid * 6 + 3;
        sysstoref(h, o_r[3]); sysstoref(h+1, o_u[3]); sysstoref(h+2, o_p[3]);
    }
    nm = wave_max(nm);
    if ((tid & 63) == 0) red[tid >> 6] = nm;
    __syncthreads();
    if (tid == 0)
        sysmaxu(&slots[(size_t)(k + 1) * SLOTW + (bid & (SLOTW - 1))],
                __float_as_uint(fmaxf(fmaxf(red[0], red[1]),
                                      fmaxf(red[2], red[3]))));
    return dt;
}

__global__ __launch_bounds__(BLK, 4) void euler_pers(
        const float* __restrict__ rho0, const float* __restrict__ u0,
        const float* __restrict__ p0, const float* __restrict__ tf,
        float* __restrict__ A, float* __restrict__ B,
        unsigned* __restrict__ slots, float* __restrict__ halo,
        unsigned* __restrict__ bar) {
    __shared__ float red[4];
    const int tid = threadIdx.x, bid = blockIdx.x;
    unsigned gen = 0;
    prepass_core(rho0, u0, p0, slots, red);
    float t = 0.f;
    const float tfin = *tf;
    gbar<64, 16, 64>(bar, bid, ++gen);
    for (int k = 0; k < NSTEPS; ++k) {
        const int pk = k & 1;
        const float *rs, *us, *ps;
        if (k == 0) { rs = rho0; us = u0; ps = p0; }
        else { const float* s = pk ? B : A; rs = s; us = s + NXC; ps = s + 2*NXC; }
        float* dst = pk ? A : B;
        const float* hin = halo + (size_t)pk * (NBLK * 6);
        float* hout = halo + (size_t)(1 - pk) * (NBLK * 6);
        float dt = step_core(k, bid, tid, rs, us, ps, dst, hin, hout,
                             slots, t, tfin, red);
        t += dt;
        if (k < NSTEPS - 1) gbar<64, 16, 64>(bar, bid, ++gen);
    }
}

__global__ __launch_bounds__(BLK) void prepass_k(
        const float* __restrict__ rho0, const float* __restrict__ u0,
        const float* __restrict__ p0, unsigned* __restrict__ slots) {
    __shared__ float red[4];
    prepass_core(rho0, u0, p0, slots, red);
}

__global__ __launch_bounds__(BLK) void step_k(
        int k, const float* __restrict__ rs, const float* __restrict__ us,
        const float* __restrict__ ps, float* __restrict__ dst,
        const float* __restrict__ hin, float* __restrict__ hout,
        unsigned* __restrict__ slots, const float* __restrict__ tf,
        float* __restrict__ tbuf) {
    __shared__ float red[4];
    float t = tbuf[k];
    float dt = step_core(k, blockIdx.x, threadIdx.x, rs, us, ps, dst,
                         hin, hout, slots, t, *tf, red);
    if (blockIdx.x == 0 && threadIdx.x == 0) tbuf[k + 1] = t + dt;
}

extern "C" void kernel_launch(void* const* d_in, const int* in_sizes, int n_in,
                              void* d_out, int out_size, void* d_ws, size_t ws_size,
                              hipStream_t stream) {
    const float* rho0 = (const float*)d_in[0];
    const float* u0   = (const float*)d_in[1];
    const float* p0   = (const float*)d_in[2];
    const float* tf   = (const float*)d_in[3];
    // d_in[4] = n_steps (fixed at 32)

    float* A        = (float*)d_out;
    float* B        = (float*)d_ws;                          // 3*NXC floats
    unsigned* ctrl  = (unsigned*)(B + (size_t)3 * NXC);      // CTRL_TOTAL
    unsigned* bar   = ctrl + CTRL_BAR;
    unsigned* slots = ctrl + CTRL_SLOTS;
    float* tbuf     = (float*)(ctrl + CTRL_TBUF);
    float* haloA    = (float*)(ctrl + CTRL_TOTAL);           // 33*ANBLK*6
    float* haloB    = haloA + (size_t)NSLOT * ANBLK * 6;     // 2*NBLK*6

    ws_zero<<<1, 256, 0, stream>>>(ctrl);

    int dev = 0; (void)hipGetDevice(&dev);
    int cus = 0;
    (void)hipDeviceGetAttribute(&cus, hipDeviceAttributeMultiprocessorCount, dev);

    bool done = false;
    int occA = 0;
    (void)hipOccupancyMaxActiveBlocksPerMultiprocessor(&occA, euler_async, ABLK, 0);
    if (occA > 0 && cus > 0 && (long)occA * cus >= ANBLK) {
        void* args[] = {(void*)&rho0, (void*)&u0, (void*)&p0, (void*)&tf,
                        (void*)&A, (void*)&ctrl, (void*)&haloA};
        done = hipLaunchCooperativeKernel((void*)euler_async, dim3(ANBLK),
                                          dim3(ABLK), args, 0, stream)
               == hipSuccess;
    }
    if (!done) {
        int occB = 0;
        (void)hipOccupancyMaxActiveBlocksPerMultiprocessor(&occB, euler_pers, BLK, 0);
        if (occB > 0 && cus > 0 && (long)occB * cus >= NBLK) {
            void* args[] = {(void*)&rho0, (void*)&u0, (void*)&p0, (void*)&tf,
                            (void*)&A, (void*)&B, (void*)&slots, (void*)&haloB,
                            (void*)&bar};
            done = hipLaunchCooperativeKernel((void*)euler_pers, dim3(NBLK),
                                              dim3(BLK), args, 0, stream)
                   == hipSuccess;
        }
    }
    if (!done) {
        prepass_k<<<NBLK, BLK, 0, stream>>>(rho0, u0, p0, slots);
        for (int k = 0; k < NSTEPS; ++k) {
            const int pk = k & 1;
            const float *rs, *us, *ps;
            if (k == 0) { rs = rho0; us = u0; ps = p0; }
            else { const float* s = pk ? B : A; rs = s; us = s + NXC; ps = s + 2*NXC; }
            float* dst = pk ? A : B;
            const float* hin = haloB + (size_t)pk * (NBLK * 6);
            float* hout = haloB + (size_t)(1 - pk) * (NBLK * 6);
            step_k<<<NBLK, BLK, 0, stream>>>(k, rs, us, ps, dst, hin, hout,
                                             slots, tf, tbuf);
        }
    }
}

// Round 11
// 308.194 us; speedup vs baseline: 1.3065x; 1.3065x over previous
//
#include <hip/hip_runtime.h>

// 1D Euler, Roe flux + Harten entropy fix, 32 steps. Round 11:
// round-10's ASYNC DATAFLOW kernel, launched UNCONDITIONALLY.
//
// Round 8/9/10 forensics: bench times were 399/400/403 us (identical) while
// profiled kernels were 307/796/220 us. The host-side occupancy queries
// added in round 8 FAIL during stream capture -> the captured (timed) graph
// silently fell back to the 33-dispatch path (~400 us) every round, while
// rocprof profiled the direct correctness calls (where the query succeeds
// and the coop kernel runs). Rounds 2/3/4/7 (unconditional coop launch, no
// host queries) all captured correctly with bench = kernel + 55-90 us.
// Round 10's euler_async is PROVEN: launches at 256x1024 (64 VGPR, 25 KB
// LDS), runs 220 us, passes validation. So: no queries, no fallbacks.
//
// Kernel design (unchanged from round 10 variant A):
//  - Thread owns 4 cells in VGPRs for all 32 steps. In-block neighbors via
//    LDS; block edges via per-step (never reused) IC halo rows published
//    with a monotone hflag -- only the 2 edge threads of each neighbor poll.
//  - dt: leader does slotMax(row k+1) then done[k+1]++ (data-dep ordered);
//    256th incrementer fans ready=k+2 out to 8 padded copies. Only wave 0
//    polls ready + reads the 64 slots (one coalesced burst), broadcasts
//    amax via LDS. All control traffic is relaxed SYSTEM-scope (IC-coherent,
//    no buffer_wbl2/inv).
//  - Global state traffic: inputs read once, d_out written once at k=31.

#define NXC   1048576
#define GAM   1.4f
#define GM1   0.4f
#define IGM1  2.5f
#define CFLC  0.5f
#define DXC   1e-3f
#define EFIX  0.1f
#define NSTEPS 32
#define NSLOT  (NSTEPS + 1)
#define SLOTW  64
#define BSTRIDE 32             // 128 B padding between control dwords

#define ABLK  1024
#define ACPT  4
#define ATILE (ABLK*ACPT)      // 4096
#define ANBLK (NXC/ATILE)      // 256 blocks = 1/CU

__device__ __forceinline__ float frcp(float x){ return __builtin_amdgcn_rcpf(x); }
__device__ __forceinline__ float frsq(float x){ return __builtin_amdgcn_rsqf(x); }
__device__ __forceinline__ float fsqrt_(float x){ return __builtin_amdgcn_sqrtf(x); }

__device__ __forceinline__ float sysloadf(const float* p) {
    return __hip_atomic_load(p, __ATOMIC_RELAXED, __HIP_MEMORY_SCOPE_SYSTEM);
}
__device__ __forceinline__ void sysstoref(float* p, float v) {
    __hip_atomic_store(p, v, __ATOMIC_RELAXED, __HIP_MEMORY_SCOPE_SYSTEM);
}
__device__ __forceinline__ unsigned sysloadu(const unsigned* p) {
    return __hip_atomic_load(p, __ATOMIC_RELAXED, __HIP_MEMORY_SCOPE_SYSTEM);
}
__device__ __forceinline__ void sysstoreu(unsigned* p, unsigned v) {
    __hip_atomic_store(p, v, __ATOMIC_RELAXED, __HIP_MEMORY_SCOPE_SYSTEM);
}
__device__ __forceinline__ unsigned sysmaxu(unsigned* p, unsigned v) {
    return __hip_atomic_fetch_max(p, v, __ATOMIC_RELAXED,
                                  __HIP_MEMORY_SCOPE_SYSTEM);
}
__device__ __forceinline__ unsigned sysaddu(unsigned* p, unsigned v) {
    return __hip_atomic_fetch_add(p, v, __ATOMIC_RELAXED,
                                  __HIP_MEMORY_SCOPE_SYSTEM);
}
__device__ __forceinline__ void pollge(const unsigned* p, unsigned tgt) {
    while (sysloadu(p) < tgt) __builtin_amdgcn_s_sleep(1);
}

__device__ __forceinline__ float wave_max(float v) {
    #pragma unroll
    for (int k = 32; k >= 1; k >>= 1)
        v = fmaxf(v, __shfl_xor(v, k));
    return v;
}

// ctrl layout (uints): slots 33*64 | done 33*32 | ready 8*32 | hflag 256*32
#define CTRL_SLOTS 0
#define CTRL_DONE  (CTRL_SLOTS + NSLOT*SLOTW)
#define CTRL_READY (CTRL_DONE + NSLOT*BSTRIDE)
#define CTRL_HFLAG (CTRL_READY + 8*BSTRIDE)
#define CTRL_TOTAL (CTRL_HFLAG + ANBLK*BSTRIDE)

__global__ void ws_zero(unsigned* z) {
    for (int i = threadIdx.x; i < CTRL_TOTAL; i += 256) z[i] = 0u;
}

__device__ __forceinline__ void roe5(const float rr[6], const float uu[6],
                                     const float pp[6], const float ss[6],
                                     const float gg[6],
                                     float Fr[5], float Fm[5], float Fe[5]) {
    #pragma unroll
    for (int j = 0; j < 5; ++j) {
        float sL = ss[j], sR = ss[j + 1];
        float uL = uu[j], uR = uu[j + 1];
        float invden = frcp(sL + sR);
        float ur = (sL * uL + sR * uR) * invden;
        float Hr = (gg[j] + gg[j + 1]) * invden;
        float c  = fsqrt_(fmaxf(GM1 * (Hr - 0.5f * ur * ur), 1e-10f));
        float eps = EFIX * c;
        float l1 = ur - c, l3 = ur + c;
        float a1 = fsqrt_(l1 * l1 + eps * eps);
        float a2 = fsqrt_(ur * ur + eps * eps);
        float a3 = fsqrt_(l3 * l3 + eps * eps);
        float drho = rr[j + 1] - rr[j];
        float du   = uR - uL;
        float dp   = pp[j + 1] - pp[j];
        float c2 = c * c;
        float inv2c2 = frcp(c2 + c2);
        float al2 = drho - (dp + dp) * inv2c2;
        float tcd = c * rr[j + 1] * du;
        float al1 = (dp - tcd) * inv2c2;
        float al3 = (dp + tcd) * inv2c2;
        float FrL = rr[j] * uL, FrR = rr[j + 1] * uR;
        float FmL = FrL * uL + pp[j], FmR = FrR * uR + pp[j + 1];
        float FeL = uL * (gg[j] * sL), FeR = uR * (gg[j + 1] * sR);
        float w1 = a1 * al1, w2 = a2 * al2, w3 = a3 * al3;
        Fr[j] = 0.5f * (FrL + FrR - (w1 + w2 + w3));
        Fm[j] = 0.5f * (FmL + FmR - (w1 * l1 + w2 * ur + w3 * l3));
        Fe[j] = 0.5f * (FeL + FeR - (w1 * (Hr - ur * c) + w2 * (0.5f * ur * ur)
                                     + w3 * (Hr + ur * c)));
    }
}

__global__ __launch_bounds__(ABLK, 4) void euler_async(
        const float* __restrict__ rho0, const float* __restrict__ u0,
        const float* __restrict__ p0, const float* __restrict__ tf,
        float* __restrict__ out, unsigned* __restrict__ ctrl,
        float* __restrict__ halo) {   // halo: NSLOT rows x ANBLK x 6
    __shared__ float Lr[ABLK], Lu[ABLK], Lp[ABLK];   // each thread's cell3
    __shared__ float Rr[ABLK], Ru[ABLK], Rp[ABLK];   // each thread's cell0
    __shared__ float red[ABLK / 64];
    __shared__ float samax;
    unsigned* slots = ctrl + CTRL_SLOTS;
    unsigned* done  = ctrl + CTRL_DONE;
    unsigned* ready = ctrl + CTRL_READY;
    unsigned* hflag = ctrl + CTRL_HFLAG;

    const int tid = threadIdx.x, bid = blockIdx.x;
    const int c0 = bid * ATILE + ACPT * tid;
    const int lane = tid & 63, wid = tid >> 6;

    float cr[4], cu[4], cp[4];

    // ---- prepass: inputs -> regs; publish halo row 0, slot row 0 ----
    {
        float4 r4 = *(const float4*)(rho0 + c0);
        float4 u4 = *(const float4*)(u0 + c0);
        float4 p4 = *(const float4*)(p0 + c0);
        cr[0]=r4.x; cr[1]=r4.y; cr[2]=r4.z; cr[3]=r4.w;
        cu[0]=u4.x; cu[1]=u4.y; cu[2]=u4.z; cu[3]=u4.w;
        cp[0]=p4.x; cp[1]=p4.y; cp[2]=p4.z; cp[3]=p4.w;
        float nm = 0.f;
        #pragma unroll
        for (int c = 0; c < 4; ++c)
            nm = fmaxf(nm, fabsf(cu[c]) + fsqrt_(GAM * cp[c] * frcp(cr[c])));
        Lr[tid]=cr[3]; Lu[tid]=cu[3]; Lp[tid]=cp[3];
        Rr[tid]=cr[0]; Ru[tid]=cu[0]; Rp[tid]=cp[0];
        if (tid == 0) {
            float* h = halo + (size_t)bid * 6;
            sysstoref(h, cr[0]); sysstoref(h+1, cu[0]); sysstoref(h+2, cp[0]);
        }
        if (tid == ABLK - 1) {
            float* h = halo + (size_t)bid * 6 + 3;
            sysstoref(h, cr[3]); sysstoref(h+1, cu[3]); sysstoref(h+2, cp[3]);
        }
        nm = wave_max(nm);
        if (lane == 0) red[wid] = nm;
        __syncthreads();            // drains halo stores (vmcnt) + red[]
        if (tid == 0) {
            float bm = red[0];
            #pragma unroll
            for (int w = 1; w < ABLK / 64; ++w) bm = fmaxf(bm, red[w]);
            sysstoreu(&hflag[bid * BSTRIDE], 1u);     // halo row 0 published
            unsigned om = sysmaxu(&slots[bid & (SLOTW - 1)],
                                  __float_as_uint(bm));
            unsigned od = sysaddu(&done[0], 1u + (om >> 31));  // dep-ordered
            if (od == ANBLK - 1) {
                unsigned v = 1u + (od >> 31);
                #pragma unroll
                for (int j = 0; j < 8; ++j) sysstoreu(&ready[j * BSTRIDE], v);
            }
        }
    }
    float t = 0.f;
    const float tfin = *tf;

    for (int k = 0; k < NSTEPS; ++k) {
        // window: idx 0..5 = cells c0-1 .. c0+4 (state k)
        float rr[6], uu[6], pp[6];
        #pragma unroll
        for (int c = 0; c < 4; ++c) { rr[c+1]=cr[c]; uu[c+1]=cu[c]; pp[c+1]=cp[c]; }
        if (tid == 0) {
            if (bid > 0) {
                pollge(&hflag[(bid - 1) * BSTRIDE], (unsigned)(k + 1));
                const float* h = halo + ((size_t)k * ANBLK + (bid - 1)) * 6 + 3;
                rr[0]=sysloadf(h); uu[0]=sysloadf(h+1); pp[0]=sysloadf(h+2);
            } else { rr[0]=cr[0]; uu[0]=cu[0]; pp[0]=cp[0]; }
        } else { rr[0]=Lr[tid-1]; uu[0]=Lu[tid-1]; pp[0]=Lp[tid-1]; }
        if (tid == ABLK - 1) {
            if (bid < ANBLK - 1) {
                pollge(&hflag[(bid + 1) * BSTRIDE], (unsigned)(k + 1));
                const float* h = halo + ((size_t)k * ANBLK + (bid + 1)) * 6;
                rr[5]=sysloadf(h); uu[5]=sysloadf(h+1); pp[5]=sysloadf(h+2);
            } else { rr[5]=cr[3]; uu[5]=cu[3]; pp[5]=cp[3]; }
        } else { rr[5]=Rr[tid+1]; uu[5]=Ru[tid+1]; pp[5]=Rp[tid+1]; }

        // flux compute (overlaps wave0's later ready-poll on other waves)
        float ss[6], gg[6];
        #pragma unroll
        for (int i = 0; i < 6; ++i) {
            float E = pp[i] * IGM1 + 0.5f * rr[i] * uu[i] * uu[i];
            float q = frsq(rr[i]);
            ss[i] = rr[i] * q;
            gg[i] = (E + pp[i]) * q;
        }
        float Fr[5], Fm[5], Fe[5];
        roe5(rr, uu, pp, ss, gg, Fr, Fm, Fe);

        // wave 0: wait for slot row k finality, read 64 slots, broadcast
        if (wid == 0) {
            pollge(&ready[(bid & 7) * BSTRIDE], (unsigned)(k + 1));
            float av = __uint_as_float(sysloadu(&slots[(size_t)k * SLOTW + lane]));
            float am = wave_max(av);
            if (lane == 0) samax = am;
        }
        __syncthreads();     // #1: samax ready; all LDS neighbor reads done

        float amax = samax;
        float dt = fminf(CFLC * DXC / amax, fmaxf(tfin - t, 0.f));
        t += dt;
        float dtdx = dt / DXC;

        float nm = 0.f;
        #pragma unroll
        for (int i = 1; i <= 4; ++i) {
            float E  = gg[i] * ss[i] - pp[i];           // (E+p) - p
            float r2 = rr[i]         - dtdx * (Fr[i] - Fr[i-1]);
            float m2 = rr[i] * uu[i] - dtdx * (Fm[i] - Fm[i-1]);
            float E2 = E             - dtdx * (Fe[i] - Fe[i-1]);
            float q2 = frsq(r2);
            float ir = q2 * q2;
            float u2 = m2 * ir;
            float p2 = GM1 * (E2 - 0.5f * r2 * u2 * u2);
            cr[i-1]=r2; cu[i-1]=u2; cp[i-1]=p2;
            nm = fmaxf(nm, fabsf(u2) + fsqrt_(GAM * p2 * ir));
        }

        if (k < NSTEPS - 1) {
            Lr[tid]=cr[3]; Lu[tid]=cu[3]; Lp[tid]=cp[3];
            Rr[tid]=cr[0]; Ru[tid]=cu[0]; Rp[tid]=cp[0];
            if (tid == 0) {
                float* h = halo + ((size_t)(k + 1) * ANBLK + bid) * 6;
                sysstoref(h, cr[0]); sysstoref(h+1, cu[0]); sysstoref(h+2, cp[0]);
            }
            if (tid == ABLK - 1) {
                float* h = halo + ((size_t)(k + 1) * ANBLK + bid) * 6 + 3;
                sysstoref(h, cr[3]); sysstoref(h+1, cu[3]); sysstoref(h+2, cp[3]);
            }
            nm = wave_max(nm);
            if (lane == 0) red[wid] = nm;
            __syncthreads();   // #2: drains halo stores; LDS visible next step
            if (tid == 0) {
                float bm = red[0];
                #pragma unroll
                for (int w = 1; w < ABLK / 64; ++w) bm = fmaxf(bm, red[w]);
                sysstoreu(&hflag[bid * BSTRIDE], (unsigned)(k + 2));
                unsigned om = sysmaxu(&slots[(size_t)(k + 1) * SLOTW
                                             + (bid & (SLOTW - 1))],
                                      __float_as_uint(bm));
                unsigned od = sysaddu(&done[(size_t)(k + 1) * BSTRIDE],
                                      1u + (om >> 31));
                if (od == ANBLK - 1) {
                    unsigned v = (unsigned)(k + 2) + (od >> 31);
                    #pragma unroll
                    for (int j = 0; j < 8; ++j)
                        sysstoreu(&ready[j * BSTRIDE], v);
                }
            }
        } else {
            *(float4*)(out + c0)         = make_float4(cr[0], cr[1], cr[2], cr[3]);
            *(float4*)(out + NXC + c0)   = make_float4(cu[0], cu[1], cu[2], cu[3]);
            *(float4*)(out + 2*NXC + c0) = make_float4(cp[0], cp[1], cp[2], cp[3]);
        }
    }
}

extern "C" void kernel_launch(void* const* d_in, const int* in_sizes, int n_in,
                              void* d_out, int out_size, void* d_ws, size_t ws_size,
                              hipStream_t stream) {
    const float* rho0 = (const float*)d_in[0];
    const float* u0   = (const float*)d_in[1];
    const float* p0   = (const float*)d_in[2];
    const float* tf   = (const float*)d_in[3];
    // d_in[4] = n_steps (fixed at 32)

    float* out      = (float*)d_out;
    unsigned* ctrl  = (unsigned*)d_ws;                      // CTRL_TOTAL uints
    float* halo     = (float*)(ctrl + CTRL_TOTAL);          // 33*ANBLK*6 floats

    ws_zero<<<1, 256, 0, stream>>>(ctrl);

    // Unconditional cooperative launch — NO host queries inside
    // kernel_launch (they fail during stream capture and silently swapped
    // the timed graph to a slow fallback in rounds 8-10). This exact kernel
    // shape (256 blocks x 1024 thr, 64 VGPR, 25 KB LDS) is HW-proven to
    // launch and run (rounds 9/10 profiles).
    void* args[] = {(void*)&rho0, (void*)&u0, (void*)&p0, (void*)&tf,
                    (void*)&out, (void*)&ctrl, (void*)&halo};
    hipLaunchCooperativeKernel((void*)euler_async, dim3(ANBLK), dim3(ABLK),
                               args, 0, stream);
}

// Round 12
// 238.273 us; speedup vs baseline: 1.6898x; 1.2935x over previous
//
#include <hip/hip_runtime.h>

// 1D Euler, Roe flux + Harten entropy fix, 32 steps. Round 12:
// ONE-HOP dt protocol + LDS flux exchange, on round-11's proven skeleton.
//
// Round-11 ledger: bench 308 = kernel 221 + ~87 us harness. VALU issue
// ~3.4 us/step; ~3.5 us/step is the dt finality chain (atomicMax -> done
// add -> ready fanout -> poll -> slot read = 4-5 dependent IC round trips).
// This round:
//  - bmax[33][256]: leader plain-stores its block max (float bits, sign
//    CLEAR) once per row. Consumers poll SIGN BITS: harness poison
//    0xAAAAAAAA and the init-fill are sign-SET = unpublished. Wave 0 polls
//    4 entries/lane (all 256) with __all, then maxes them directly -- dt is
//    bit-identical (fmax is exact, order-free). One store->load hop.
//    The same sign-poll on bmax[row][b+-1] is the halo-ready flag (halo
//    stores drain before the leader publish via __syncthreads vmcnt drain,
//    the pattern proven since round 4).
//  - Flux redundancy removed: thread computes fluxes 0..3, reads flux 4
//    from tid+1 via LDS (bit-identical recompute -> bit-identical value);
//    tid==ABLK-1 computes its own. RAW/WAR covered by the existing two
//    syncthreads per step.
//  - State in VGPRs all 32 steps; inputs read once; d_out written once.

#define NXC   1048576
#define GAM   1.4f
#define GM1   0.4f
#define IGM1  2.5f
#define CFLC  0.5f
#define DXC   1e-3f
#define EFIX  0.1f
#define NSTEPS 32
#define NSLOT  (NSTEPS + 1)

#define ABLK  1024
#define ACPT  4
#define ATILE (ABLK*ACPT)      // 4096
#define ANBLK (NXC/ATILE)      // 256 blocks = 1/CU (proven shape r9-r11)

__device__ __forceinline__ float frcp(float x){ return __builtin_amdgcn_rcpf(x); }
__device__ __forceinline__ float frsq(float x){ return __builtin_amdgcn_rsqf(x); }
__device__ __forceinline__ float fsqrt_(float x){ return __builtin_amdgcn_sqrtf(x); }

__device__ __forceinline__ float sysloadf(const float* p) {
    return __hip_atomic_load(p, __ATOMIC_RELAXED, __HIP_MEMORY_SCOPE_SYSTEM);
}
__device__ __forceinline__ void sysstoref(float* p, float v) {
    __hip_atomic_store(p, v, __ATOMIC_RELAXED, __HIP_MEMORY_SCOPE_SYSTEM);
}
__device__ __forceinline__ unsigned sysloadu(const unsigned* p) {
    return __hip_atomic_load(p, __ATOMIC_RELAXED, __HIP_MEMORY_SCOPE_SYSTEM);
}
__device__ __forceinline__ void sysstoreu(unsigned* p, unsigned v) {
    __hip_atomic_store(p, v, __ATOMIC_RELAXED, __HIP_MEMORY_SCOPE_SYSTEM);
}

__device__ __forceinline__ float wave_max(float v) {
    #pragma unroll
    for (int k = 32; k >= 1; k >>= 1)
        v = fmaxf(v, __shfl_xor(v, k));
    return v;
}

// bmax: NSLOT rows x ANBLK entries (unpadded; wave-0 reads them as 4/lane).
#define CTRL_TOTAL (NSLOT * ANBLK)

// Fill bmax with sign-SET sentinel: deterministic "unpublished" regardless
// of prior ws contents (poison 0xAA is also sign-set, but don't rely on it).
__global__ void bmax_init(unsigned* z) {
    for (int i = threadIdx.x; i < CTRL_TOTAL; i += 256) z[i] = 0xAAAAAAAAu;
}

// One Roe flux from window-index j (cells j | j+1).
__device__ __forceinline__ void roe1(const float rr[6], const float uu[6],
                                     const float pp[6], const float ss[6],
                                     const float gg[6], int j,
                                     float& Frj, float& Fmj, float& Fej) {
    float sL = ss[j], sR = ss[j + 1];
    float uL = uu[j], uR = uu[j + 1];
    float invden = frcp(sL + sR);
    float ur = (sL * uL + sR * uR) * invden;
    float Hr = (gg[j] + gg[j + 1]) * invden;
    float c  = fsqrt_(fmaxf(GM1 * (Hr - 0.5f * ur * ur), 1e-10f));
    float eps = EFIX * c;
    float l1 = ur - c, l3 = ur + c;
    float a1 = fsqrt_(l1 * l1 + eps * eps);
    float a2 = fsqrt_(ur * ur + eps * eps);
    float a3 = fsqrt_(l3 * l3 + eps * eps);
    float drho = rr[j + 1] - rr[j];
    float du   = uR - uL;
    float dp   = pp[j + 1] - pp[j];
    float c2 = c * c;
    float inv2c2 = frcp(c2 + c2);
    float al2 = drho - (dp + dp) * inv2c2;
    float tcd = c * rr[j + 1] * du;
    float al1 = (dp - tcd) * inv2c2;
    float al3 = (dp + tcd) * inv2c2;
    float FrL = rr[j] * uL, FrR = rr[j + 1] * uR;
    float FmL = FrL * uL + pp[j], FmR = FrR * uR + pp[j + 1];
    float FeL = uL * (gg[j] * sL), FeR = uR * (gg[j + 1] * sR);
    float w1 = a1 * al1, w2 = a2 * al2, w3 = a3 * al3;
    Frj = 0.5f * (FrL + FrR - (w1 + w2 + w3));
    Fmj = 0.5f * (FmL + FmR - (w1 * l1 + w2 * ur + w3 * l3));
    Fej = 0.5f * (FeL + FeR - (w1 * (Hr - ur * c) + w2 * (0.5f * ur * ur)
                               + w3 * (Hr + ur * c)));
}

__global__ __launch_bounds__(ABLK, 4) void euler_async(
        const float* __restrict__ rho0, const float* __restrict__ u0,
        const float* __restrict__ p0, const float* __restrict__ tf,
        float* __restrict__ out, unsigned* __restrict__ bmax,
        float* __restrict__ halo) {   // halo: NSLOT rows x ANBLK x 6
    __shared__ float Lr[ABLK], Lu[ABLK], Lp[ABLK];   // each thread's cell3
    __shared__ float Rr[ABLK], Ru[ABLK], Rp[ABLK];   // each thread's cell0
    __shared__ float fxr[ABLK], fxm[ABLK], fxe[ABLK]; // each thread's flux0
    __shared__ float red[ABLK / 64];
    __shared__ float samax;

    const int tid = threadIdx.x, bid = blockIdx.x;
    const int c0 = bid * ATILE + ACPT * tid;
    const int lane = tid & 63, wid = tid >> 6;

    float cr[4], cu[4], cp[4];

    // ---- prepass: inputs -> regs; publish halo row 0 + bmax row 0 ----
    {
        float4 r4 = *(const float4*)(rho0 + c0);
        float4 u4 = *(const float4*)(u0 + c0);
        float4 p4 = *(const float4*)(p0 + c0);
        cr[0]=r4.x; cr[1]=r4.y; cr[2]=r4.z; cr[3]=r4.w;
        cu[0]=u4.x; cu[1]=u4.y; cu[2]=u4.z; cu[3]=u4.w;
        cp[0]=p4.x; cp[1]=p4.y; cp[2]=p4.z; cp[3]=p4.w;
        float nm = 0.f;
        #pragma unroll
        for (int c = 0; c < 4; ++c)
            nm = fmaxf(nm, fabsf(cu[c]) + fsqrt_(GAM * cp[c] * frcp(cr[c])));
        Lr[tid]=cr[3]; Lu[tid]=cu[3]; Lp[tid]=cp[3];
        Rr[tid]=cr[0]; Ru[tid]=cu[0]; Rp[tid]=cp[0];
        if (tid == 0) {
            float* h = halo + (size_t)bid * 6;
            sysstoref(h, cr[0]); sysstoref(h+1, cu[0]); sysstoref(h+2, cp[0]);
        }
        if (tid == ABLK - 1) {
            float* h = halo + (size_t)bid * 6 + 3;
            sysstoref(h, cr[3]); sysstoref(h+1, cu[3]); sysstoref(h+2, cp[3]);
        }
        nm = wave_max(nm);
        if (lane == 0) red[wid] = nm;
        __syncthreads();      // drains every wave's halo stores + red[]
        if (tid == 0) {
            float bm = red[0];
            #pragma unroll
            for (int w = 1; w < ABLK / 64; ++w) bm = fmaxf(bm, red[w]);
            sysstoreu(&bmax[bid], __float_as_uint(bm));   // sign clear
        }
    }
    float t = 0.f;
    const float tfin = *tf;

    for (int k = 0; k < NSTEPS; ++k) {
        const unsigned* brow = bmax + (size_t)k * ANBLK;

        // window: idx 0..5 = cells c0-1 .. c0+4 (state k)
        float rr[6], uu[6], pp[6];
        #pragma unroll
        for (int c = 0; c < 4; ++c) { rr[c+1]=cr[c]; uu[c+1]=cu[c]; pp[c+1]=cp[c]; }
        if (tid == 0) {
            if (bid > 0) {   // neighbor's bmax publish implies its halo row k
                while (sysloadu(&brow[bid - 1]) & 0x80000000u)
                    __builtin_amdgcn_s_sleep(1);
                const float* h = halo + ((size_t)k * ANBLK + (bid - 1)) * 6 + 3;
                rr[0]=sysloadf(h); uu[0]=sysloadf(h+1); pp[0]=sysloadf(h+2);
            } else { rr[0]=cr[0]; uu[0]=cu[0]; pp[0]=cp[0]; }
        } else { rr[0]=Lr[tid-1]; uu[0]=Lu[tid-1]; pp[0]=Lp[tid-1]; }
        if (tid == ABLK - 1) {
            if (bid < ANBLK - 1) {
                while (sysloadu(&brow[bid + 1]) & 0x80000000u)
                    __builtin_amdgcn_s_sleep(1);
                const float* h = halo + ((size_t)k * ANBLK + (bid + 1)) * 6;
                rr[5]=sysloadf(h); uu[5]=sysloadf(h+1); pp[5]=sysloadf(h+2);
            } else { rr[5]=cr[3]; uu[5]=cu[3]; pp[5]=cp[3]; }
        } else { rr[5]=Rr[tid+1]; uu[5]=Ru[tid+1]; pp[5]=Rp[tid+1]; }

        // precompute + fluxes 0..3; flux 4 comes from tid+1 via LDS
        float ss[6], gg[6];
        #pragma unroll
        for (int i = 0; i < 6; ++i) {
            float E = pp[i] * IGM1 + 0.5f * rr[i] * uu[i] * uu[i];
            float q = frsq(rr[i]);
            ss[i] = rr[i] * q;
            gg[i] = (E + pp[i]) * q;
        }
        float Fr[5], Fm[5], Fe[5];
        #pragma unroll
        for (int j = 0; j < 4; ++j)
            roe1(rr, uu, pp, ss, gg, j, Fr[j], Fm[j], Fe[j]);
        fxr[tid] = Fr[0]; fxm[tid] = Fm[0]; fxe[tid] = Fe[0];
        if (tid == ABLK - 1)          // block-edge interface: compute own
            roe1(rr, uu, pp, ss, gg, 4, Fr[4], Fm[4], Fe[4]);

        // wave 0: poll all 256 bmax entries sign-clear (4/lane), then max
        if (wid == 0) {
            unsigned v0, v1, v2, v3;
            for (;;) {
                v0 = sysloadu(&brow[lane * 4 + 0]);
                v1 = sysloadu(&brow[lane * 4 + 1]);
                v2 = sysloadu(&brow[lane * 4 + 2]);
                v3 = sysloadu(&brow[lane * 4 + 3]);
                if (__all(((v0 | v1 | v2 | v3) & 0x80000000u) == 0u)) break;
                __builtin_amdgcn_s_sleep(1);
            }
            float m = fmaxf(fmaxf(__uint_as_float(v0), __uint_as_float(v1)),
                            fmaxf(__uint_as_float(v2), __uint_as_float(v3)));
            m = wave_max(m);
            if (lane == 0) samax = m;
        }
        __syncthreads();   // #1: samax + flux LDS ready; state LDS reads done

        if (tid < ABLK - 1) {
            Fr[4] = fxr[tid + 1]; Fm[4] = fxm[tid + 1]; Fe[4] = fxe[tid + 1];
        }
        float amax = samax;
        float dt = fminf(CFLC * DXC / amax, fmaxf(tfin - t, 0.f));
        t += dt;
        float dtdx = dt / DXC;

        float nm = 0.f;
        #pragma unroll
        for (int i = 1; i <= 4; ++i) {
            float E  = gg[i] * ss[i] - pp[i];           // (E+p) - p
            float r2 = rr[i]         - dtdx * (Fr[i] - Fr[i-1]);
            float m2 = rr[i] * uu[i] - dtdx * (Fm[i] - Fm[i-1]);
            float E2 = E             - dtdx * (Fe[i] - Fe[i-1]);
            float q2 = frsq(r2);
            float ir = q2 * q2;
            float u2 = m2 * ir;
            float p2 = GM1 * (E2 - 0.5f * r2 * u2 * u2);
            cr[i-1]=r2; cu[i-1]=u2; cp[i-1]=p2;
            nm = fmaxf(nm, fabsf(u2) + fsqrt_(GAM * p2 * ir));
        }

        if (k < NSTEPS - 1) {
            Lr[tid]=cr[3]; Lu[tid]=cu[3]; Lp[tid]=cp[3];
            Rr[tid]=cr[0]; Ru[tid]=cu[0]; Rp[tid]=cp[0];
            if (tid == 0) {
                float* h = halo + ((size_t)(k + 1) * ANBLK + bid) * 6;
                sysstoref(h, cr[0]); sysstoref(h+1, cu[0]); sysstoref(h+2, cp[0]);
            }
            if (tid == ABLK - 1) {
                float* h = halo + ((size_t)(k + 1) * ANBLK + bid) * 6 + 3;
                sysstoref(h, cr[3]); sysstoref(h+1, cu[3]); sysstoref(h+2, cp[3]);
            }
            nm = wave_max(nm);
            if (lane == 0) red[wid] = nm;
            __syncthreads();   // #2: drains halo stores; LDS ready for k+1
            if (tid == 0) {
                float bm = red[0];
                #pragma unroll
                for (int w = 1; w < ABLK / 64; ++w) bm = fmaxf(bm, red[w]);
                sysstoreu(&bmax[(size_t)(k + 1) * ANBLK + bid],
                          __float_as_uint(bm));          // sign clear
            }
        } else {
            *(float4*)(out + c0)         = make_float4(cr[0], cr[1], cr[2], cr[3]);
            *(float4*)(out + NXC + c0)   = make_float4(cu[0], cu[1], cu[2], cu[3]);
            *(float4*)(out + 2*NXC + c0) = make_float4(cp[0], cp[1], cp[2], cp[3]);
        }
    }
}

extern "C" void kernel_launch(void* const* d_in, const int* in_sizes, int n_in,
                              void* d_out, int out_size, void* d_ws, size_t ws_size,
                              hipStream_t stream) {
    const float* rho0 = (const float*)d_in[0];
    const float* u0   = (const float*)d_in[1];
    const float* p0   = (const float*)d_in[2];
    const float* tf   = (const float*)d_in[3];
    // d_in[4] = n_steps (fixed at 32)

    float* out      = (float*)d_out;
    unsigned* bmax  = (unsigned*)d_ws;                   // 33*256 uints
    float* halo     = (float*)(bmax + CTRL_TOTAL);       // 33*256*6 floats

    bmax_init<<<1, 256, 0, stream>>>(bmax);

    // Unconditional cooperative launch (no host queries: they fail during
    // stream capture and silently swap the timed graph -- round-11 lesson).
    void* args[] = {(void*)&rho0, (void*)&u0, (void*)&p0, (void*)&tf,
                    (void*)&out, (void*)&bmax, (void*)&halo};
    hipLaunchCooperativeKernel((void*)euler_async, dim3(ANBLK), dim3(ABLK),
                               args, 0, stream);
}